// Round 2
// baseline (5009.671 us; speedup 1.0000x reference)
//
#include <hip/hip_runtime.h>
#include <hip/hip_bf16.h>
#include <math.h>

typedef __attribute__((ext_vector_type(8))) short short8;
typedef __attribute__((ext_vector_type(4))) float f32x4;

#define MU_   0.1f
#define THR_  0.01f
#define ZB_   5916        // zero blocks: 1,514,496 float4 / 256
#define GRID_ 896

static __device__ inline short f2bf(float f) {
    __hip_bfloat16 h = __float2bfloat16(f);
    return *reinterpret_cast<short*>(&h);
}
static __device__ inline float bf2f(unsigned short u) {
    unsigned int x = ((unsigned int)u) << 16;
    return __builtin_bit_cast(float, x);
}

// ---------------------------------------------------------------------------
// Grid barrier: monotonic counter, 1 arrive + 1 poller per block.
// __threadfence (agent scope) gives cross-XCD release/acquire (wb/inv L2).
// All 896 blocks are co-resident (LDS 29.4KB -> 5/CU, VGPR<=128 -> 4/CU).
// ---------------------------------------------------------------------------
static __device__ __forceinline__ void gbar(unsigned* cnt, unsigned target) {
    __threadfence();                 // release this block's writes
    __syncthreads();
    if (threadIdx.x == 0) {
        __hip_atomic_fetch_add(cnt, 1u, __ATOMIC_RELEASE, __HIP_MEMORY_SCOPE_AGENT);
        while (__hip_atomic_load(cnt, __ATOMIC_ACQUIRE, __HIP_MEMORY_SCOPE_AGENT) < target)
            __builtin_amdgcn_s_sleep(32);
    }
    __syncthreads();
    __threadfence();                 // acquire: invalidate stale caches
}

// ---------------------------------------------------------------------------
// prep virtual block: [0,ZB_) zero Rp+Yp; [ZB_,ZB_+32) wnorm; rest pack_x.
// ---------------------------------------------------------------------------
static __device__ __forceinline__ void prep_vb(
    int vb, int tid, short* smem,
    const float* __restrict__ x, const float* __restrict__ W,
    float4* __restrict__ zbase, int n4,
    short* __restrict__ Xp, short* __restrict__ Wf2, short* __restrict__ Wt2) {
    float* lx = (float*)smem;                       // 64*57 floats = 14592 B
    if (vb < ZB_) {
        int i = vb * 256 + tid;
        if (i < n4) zbase[i] = make_float4(0.f, 0.f, 0.f, 0.f);
    } else if (vb < ZB_ + 32) {
        int co = (vb - ZB_) * 4 + (tid >> 6);
        int ci = tid & 63;
        const float* wp = W + (co * 64 + ci) * 9;
        float v[9]; float s = 0.f;
#pragma unroll
        for (int t = 0; t < 9; ++t) { v[t] = wp[t]; s += v[t] * v[t]; }
#pragma unroll
        for (int off = 32; off; off >>= 1) s += __shfl_xor(s, off, 64);
        float inv = 1.0f / sqrtf(s + 1e-12f);
#pragma unroll
        for (int t = 0; t < 9; ++t) {
            Wf2[((t * 8 + (ci >> 3)) * 128 + co) * 8 + (ci & 7)] = f2bf(v[t] * inv);
            Wt2[((t * 16 + (co >> 3)) * 64 + ci) * 8 + (co & 7)] = f2bf(v[8 - t] * inv);
        }
    } else {
        int pb = vb - ZB_ - 32;
        int row = pb % 58, n = pb / 58;
        short* dst = Xp + ((size_t)(n * 58 + row) * 68) * 64;
        if (row >= 1 && row <= 56) {
            int h = row - 1;
            for (int j = tid; j < 64 * 56; j += 256) {
                int ci = j / 56, w = j - ci * 56;
                lx[ci * 57 + w] = x[((size_t)(n * 64 + ci)) * 3136 + h * 56 + w];
            }
            __syncthreads();
            for (int j = tid; j < 68 * 64; j += 256) {
                int s = j >> 6, ci = j & 63;
                float val = (s >= 2 && s < 58) ? lx[ci * 57 + (s - 2)] : 0.f;
                dst[(s << 6) + (ci ^ ((s & 7) << 3))] = f2bf(val);
            }
        } else {
            for (int j = tid; j < 68 * 64; j += 256) dst[j] = 0;
        }
    }
}

// ---------------------------------------------------------------------------
// conv_fwd body: 64->128, all 128 co per block (wave 2x2: cog x pxg).
// mode 0: c=shrink(MU*acc); y=cp=c
// mode 1: c=shrink(y_old+MU*acc); y=c+beta*(c-cp_old); cp=c
// mode 2: out=shrink(y_old+MU*acc) (fp32 NCHW, no state writes)
// ---------------------------------------------------------------------------
static __device__ __forceinline__ void conv_fwd_body(
    int bid, int tid, short* smem,
    const short* __restrict__ inp, const short* __restrict__ Wf2,
    short* __restrict__ Yp, short* __restrict__ Cp,
    float* __restrict__ outp, int mode, float beta) {
    const int sid = (bid & 7) * 112 + (bid >> 3);
    const int n = sid / 56, r = sid - n * 56 + 1;
    {   // stage B: 3 input rows, 64-short global rows -> 72-short LDS rows
        const short8* src = (const short8*)(inp + ((size_t)(n * 58 + (r - 1)) * 68) * 64);
        for (int j = tid; j < 1632; j += 256) {
            int srow = j >> 3, w = j & 7;
            *(short8*)(smem + srow * 72 + w * 8) = src[j];
        }
    }
    const int lane = tid & 63, ct = tid >> 6, quad = lane >> 4, l15 = lane & 15;
    const int cog = ct & 1, pxg = ct >> 1;
    const size_t prow = ((size_t)(n * 58 + r) * 68) * 128;

    // pre-loop coalesced prefetch of half-0 old y / c_prev (448 short8 items)
    short8 yold8[2], cold8[2];
    int pvv[2], pg[2]; bool pok[2];
#pragma unroll
    for (int k = 0; k < 2; ++k) {
        int item = tid + k * 256;
        pok[k] = item < 448;
        pvv[k] = item >> 3; pg[k] = item & 7;
        if (mode != 0 && pok[k]) {
            int s = pvv[k] + 2;
            size_t off = prow + (size_t)s * 128 + 8 * (pg[k] ^ (s & 7));
            yold8[k] = *(const short8*)(Yp + off);
            if (mode == 1) cold8[k] = *(const short8*)(Cp + off);
        }
    }
    __syncthreads();

    f32x4 acc[2][4];
#pragma unroll
    for (int pt = 0; pt < 2; ++pt)
#pragma unroll
        for (int cot = 0; cot < 4; ++cot) acc[pt][cot] = (f32x4){0.f, 0.f, 0.f, 0.f};

#pragma unroll
    for (int f = 0; f < 18; ++f) {            // 18 k-frags, A streamed
        const int t = f >> 1, half = f & 1;
        const int dh = t / 3, dw = t % 3;
        const int u = l15 + dw + 1;
        const int phys = (half * 4 + quad) ^ (u & 7);
        short8 areg[4];
#pragma unroll
        for (int cot = 0; cot < 4; ++cot) {
            const int co = cog * 64 + cot * 16 + l15;
            areg[cot] = *(const short8*)(Wf2 +
                ((size_t)((t * 8 + half * 4 + quad) * 128 + co)) * 8);
        }
#pragma unroll
        for (int pt = 0; pt < 2; ++pt) {
            const int pti = pxg * 2 + pt;
            const short8 bv = *(const short8*)(smem +
                (dh * 68 + pti * 16 + u) * 72 + phys * 8);
#pragma unroll
            for (int cot = 0; cot < 4; ++cot)
                acc[pt][cot] = __builtin_amdgcn_mfma_f32_16x16x32_bf16(areg[cot], bv, acc[pt][cot], 0, 0, 0);
        }
    }

    // ---- epilogue: per-half state bounce via LDS (smem dead) ----
    __syncthreads();
    short* tb_y = smem;              // [64 px][72 ch-half]
    short* tb_c = smem + 4608;
    const int h = r - 1;
#pragma unroll
    for (int hh = 0; hh < 2; ++hh) {
        if (mode != 0) {
#pragma unroll
            for (int k = 0; k < 2; ++k) if (pok[k]) {
                int o = pvv[k] * 72 + 8 * (pg[k] ^ (pvv[k] & 3));
                *(short8*)(tb_y + o) = yold8[k];
                if (mode == 1) *(short8*)(tb_c + o) = cold8[k];
            }
        }
        __syncthreads();
        // issue half-1 loads early; latency hides under half-0 processing
        if (hh == 0 && mode != 0) {
#pragma unroll
            for (int k = 0; k < 2; ++k) if (pok[k]) {
                int s = pvv[k] + 2;
                size_t off = prow + (size_t)s * 128 + 8 * ((pg[k] + 8) ^ (s & 7));
                yold8[k] = *(const short8*)(Yp + off);
                if (mode == 1) cold8[k] = *(const short8*)(Cp + off);
            }
        }
        if (cog == hh) {
#pragma unroll
            for (int pt = 0; pt < 2; ++pt) {
                const int px = pxg * 32 + pt * 16 + l15;
#pragma unroll
                for (int cot = 0; cot < 4; ++cot) {
#pragma unroll
                    for (int reg = 0; reg < 4; ++reg) {
                        const int lch = cot * 16 + quad * 4 + reg;   // 0..63
                        const int slot = px * 72 + (lch ^ ((px & 3) << 3));
                        const float a = acc[pt][cot][reg];
                        if (mode == 0) {
                            float c = fmaxf(MU_ * a - THR_, 0.f);
                            short cb16 = f2bf(c);
                            tb_y[slot] = cb16;
                            tb_c[slot] = cb16;
                        } else if (mode == 1) {
                            float yold = bf2f((unsigned short)tb_y[slot]);
                            float cold = bf2f((unsigned short)tb_c[slot]);
                            float c = fmaxf(yold + MU_ * a - THR_, 0.f);
                            tb_y[slot] = f2bf(c + beta * (c - cold));
                            tb_c[slot] = f2bf(c);
                        } else {
                            if (px < 56) {
                                float yold = bf2f((unsigned short)tb_y[slot]);
                                float c = fmaxf(yold + MU_ * a - THR_, 0.f);
                                outp[((size_t)(n * 128 + hh * 64 + lch)) * 3136 + h * 56 + px] = c;
                            }
                        }
                    }
                }
            }
        }
        if (mode != 2) {
            __syncthreads();
            for (int item = tid; item < 448; item += 256) {
                int vv = item >> 3, g = item & 7;
                int so = vv * 72 + 8 * (g ^ (vv & 3));
                short8 yv = *(const short8*)(tb_y + so);
                short8 cv = *(const short8*)(tb_c + so);
                int s = vv + 2;
                size_t off = prow + (size_t)s * 128 + 8 * ((g + 8 * hh) ^ (s & 7));
                *(short8*)(Yp + off) = yv;
                *(short8*)(Cp + off) = cv;
            }
        }
        if (hh == 0) __syncthreads();   // tables free before half-1 reuse
    }
}

// ---------------------------------------------------------------------------
// conv_t body: 128->64, wave = 64 ci x 16 px, fused residual r = x - D^T y.
// ---------------------------------------------------------------------------
static __device__ __forceinline__ void conv_t_body(
    int bid, int tid, short* smem,
    const short* __restrict__ Ypb, const short* __restrict__ Wt2,
    const short* __restrict__ Xp, short* __restrict__ Rp) {
    const int sid = (bid & 7) * 112 + (bid >> 3);
    const int n = sid / 56, r = sid - n * 56 + 1;
    const int lane = tid & 63, ct = tid >> 6, quad = lane >> 4, l15 = lane & 15;
    const short8* src = (const short8*)(Ypb + ((size_t)(n * 58 + (r - 1)) * 68) * 128);
    const size_t prow = ((size_t)(n * 58 + r) * 68) * 64;

    // pre-loop coalesced prefetch of x row (448 short8 items)
    short8 xold8[2];
    int pvv[2], pg[2]; bool pok[2];
#pragma unroll
    for (int k = 0; k < 2; ++k) {
        int item = tid + k * 256;
        pok[k] = item < 448;
        pvv[k] = item >> 3; pg[k] = item & 7;
        if (pok[k]) {
            int s = pvv[k] + 2;
            xold8[k] = *(const short8*)(Xp + prow + (size_t)s * 64 + 8 * (pg[k] ^ (s & 7)));
        }
    }

    f32x4 acc[4];                     // [cit] : 64 ci per wave, 16 px
#pragma unroll
    for (int cit = 0; cit < 4; ++cit) acc[cit] = (f32x4){0.f, 0.f, 0.f, 0.f};

#pragma unroll
    for (int p = 0; p < 2; ++p) {
        if (p) __syncthreads();      // prior pass's B reads complete
        // stage phys chunk-half p of 3 input rows (contig 128 B per 256 B row)
        for (int j = tid; j < 1632; j += 256) {
            int srow = j >> 3, w = j & 7;
            *(short8*)(smem + srow * 72 + w * 8) = src[srow * 16 + p * 8 + w];
        }
        __syncthreads();
#pragma unroll
        for (int f = 0; f < 18; ++f) {         // 18 k-frags this pass
            const int t = f >> 1, sh = f & 1;
            const int dh = t / 3, dw = t % 3;
            const int u = l15 + dw + 1;
            const int phys = (sh * 4 + quad) ^ (u & 7);
            short8 areg[4];
#pragma unroll
            for (int cit = 0; cit < 4; ++cit) {
                const int ci = cit * 16 + l15;
                areg[cit] = *(const short8*)(Wt2 +
                    ((size_t)((t * 16 + (p * 2 + sh) * 4 + quad) * 64 + ci)) * 8);
            }
            const short8 bv = *(const short8*)(smem +
                (dh * 68 + ct * 16 + u) * 72 + phys * 8);
#pragma unroll
            for (int cit = 0; cit < 4; ++cit)
                acc[cit] = __builtin_amdgcn_mfma_f32_16x16x32_bf16(areg[cit], bv, acc[cit], 0, 0, 0);
        }
    }

    // ---- epilogue: r = x - acc via LDS bounce ----
    __syncthreads();
    short* tb = smem;                // [64 px][72 ch]
#pragma unroll
    for (int k = 0; k < 2; ++k) if (pok[k]) {
        *(short8*)(tb + pvv[k] * 72 + 8 * (pg[k] ^ (pvv[k] & 3))) = xold8[k];
    }
    __syncthreads();
    {
        const int px = ct * 16 + l15;
#pragma unroll
        for (int cit = 0; cit < 4; ++cit) {
#pragma unroll
            for (int reg = 0; reg < 4; ++reg) {
                const int cir = cit * 16 + quad * 4 + reg;
                const int slot = px * 72 + (cir ^ ((px & 3) << 3));
                float xo = bf2f((unsigned short)tb[slot]);
                tb[slot] = f2bf(xo - acc[cit][reg]);
            }
        }
    }
    __syncthreads();
    for (int item = tid; item < 448; item += 256) {
        int vv = item >> 3, g = item & 7;
        short8 val = *(const short8*)(tb + vv * 72 + 8 * (g ^ (vv & 3)));
        int s = vv + 2;
        *(short8*)(Rp + prow + (size_t)s * 64 + 8 * (g ^ (s & 7))) = val;
    }
}

// ---------------------------------------------------------------------------
// Persistent FISTA: prep + 11 conv phases, grid barriers between phases.
// 896 blocks co-resident (LDS 29.4KB->5/CU, launch_bounds VGPR cap->4/CU).
// Same block -> same sid every phase: state rows stay in the XCD's L2.
// ---------------------------------------------------------------------------
__global__ __launch_bounds__(256, 4) void fista_kernel(
    const float* __restrict__ x, const float* __restrict__ W,
    float* __restrict__ out,
    short* __restrict__ Xp, short* __restrict__ Rp,
    short* __restrict__ Yp, short* __restrict__ Cp,
    short* __restrict__ Wf2, short* __restrict__ Wt2,
    unsigned* __restrict__ bar, int n4) {
    __shared__ __align__(16) short smem[14688];   // 29,376 B (lx aliases this)
    const int bid = blockIdx.x, tid = threadIdx.x;
    unsigned target = 0;

    // ---- phase 0: prep (grid-stride over 6876 virtual blocks) ----
    for (int vb = bid; vb < ZB_ + 32 + 58 * 16; vb += GRID_) {
        prep_vb(vb, tid, smem, x, W, (float4*)Rp, n4, Xp, Wf2, Wt2);
        __syncthreads();              // lx/smem safe for next vb
    }
    target += GRID_; gbar(bar, target);

    // ---- it0: c = shrink(MU * conv(x)); y = cp = c ----
    conv_fwd_body(bid, tid, smem, Xp, Wf2, Yp, Cp, (float*)nullptr, 0, 0.f);
    target += GRID_; gbar(bar, target);

    double t = 1.0;
    for (int it = 1; it <= 5; ++it) {
        conv_t_body(bid, tid, smem, Yp, Wt2, Xp, Rp);
        target += GRID_; gbar(bar, target);
        double tn = (1.0 + sqrt(1.0 + 4.0 * t * t)) / 2.0;
        float beta = (float)((t - 1.0) / tn);
        conv_fwd_body(bid, tid, smem, Rp, Wf2, Yp, Cp,
                      (it == 5) ? out : (float*)nullptr, (it == 5) ? 2 : 1, beta);
        if (it < 5) { target += GRID_; gbar(bar, target); }
        t = tn;
    }
}

// ---------------------------------------------------------------------------
extern "C" void kernel_launch(void* const* d_in, const int* in_sizes, int n_in,
                              void* d_out, int out_size, void* d_ws, size_t ws_size,
                              hipStream_t stream) {
    const float* x = (const float*)d_in[0];   // [16,64,56,56] fp32
    const float* W = (const float*)d_in[1];   // [128,64,3,3]  fp32
    float* out = (float*)d_out;               // [16,128,56,56] fp32

    // ws layout (all bf16): Xp | Rp | Yp | Cp | Wf2 | Wt2 | bar  (~49 MB)
    const size_t XPN = (size_t)16 * 58 * 68 * 64;   // 4,038,656
    const size_t YPN = 2 * XPN;                      // 8,077,312
    short* Xp = (short*)d_ws;
    short* Rp = Xp + XPN;
    short* Yp = Rp + XPN;
    short* Cp = Yp + YPN;
    short* Wf2 = Cp + YPN;                // 73728 shorts
    short* Wt2 = Wf2 + 73728;             // 73728 shorts
    unsigned* bar = (unsigned*)(Wt2 + 73728);   // 256-B aligned

    const int n4 = (int)((XPN + YPN) * 2 / 16);     // 1,514,496 (ZB_=5916)

    hipMemsetAsync(bar, 0, 64, stream);   // barrier counter = 0 (ws is poisoned)
    hipLaunchKernelGGL(fista_kernel, dim3(GRID_), dim3(256), 0, stream,
                       x, W, out, Xp, Rp, Yp, Cp, Wf2, Wt2, bar, n4);
}

// Round 3
// 1259.399 us; speedup vs baseline: 3.9778x; 3.9778x over previous
//
#include <hip/hip_runtime.h>
#include <hip/hip_bf16.h>
#include <math.h>

typedef __attribute__((ext_vector_type(8))) short short8;
typedef __attribute__((ext_vector_type(4))) float f32x4;

#define MU_  0.1f
#define THR_ 0.01f
#define ZB_  7888   // zero blocks: YA+YB = 2*8,077,312 shorts = 2,019,328 float4 / 256

static __device__ inline short f2bf(float f) {
    __hip_bfloat16 h = __float2bfloat16(f);
    return *reinterpret_cast<short*>(&h);
}
static __device__ inline float bf2f(unsigned short u) {
    unsigned int x = ((unsigned int)u) << 16;
    return __builtin_bit_cast(float, x);
}

// ---------------------------------------------------------------------------
// Merged prep: [0,ZB_) zero YA+YB (incl. pads); [ZB_,ZB_+32) wnorm; rest pack_x.
//  Wf2[t][ci>>3][co][ci&7] = Wn[co][ci*9+t]        (fwd A, k-major chunks)
//  Wt2[t][co>>3][ci][co&7] = Wn[co][ci*9+(8-t)]    (conv_t A, k-major chunks)
// ---------------------------------------------------------------------------
__global__ __launch_bounds__(256) void prep_kernel(
    const float* __restrict__ x, const float* __restrict__ W,
    float4* __restrict__ zbase, int n4,
    short* __restrict__ Xp, short* __restrict__ Wf2, short* __restrict__ Wt2) {
    __shared__ float lx[64 * 57];
    const int bid = blockIdx.x, tid = threadIdx.x;
    if (bid < ZB_) {
        int i = bid * 256 + tid;
        if (i < n4) zbase[i] = make_float4(0.f, 0.f, 0.f, 0.f);
    } else if (bid < ZB_ + 32) {
        int co = (bid - ZB_) * 4 + (tid >> 6);
        int ci = tid & 63;
        const float* wp = W + (co * 64 + ci) * 9;
        float v[9]; float s = 0.f;
#pragma unroll
        for (int t = 0; t < 9; ++t) { v[t] = wp[t]; s += v[t] * v[t]; }
#pragma unroll
        for (int off = 32; off; off >>= 1) s += __shfl_xor(s, off, 64);
        float inv = 1.0f / sqrtf(s + 1e-12f);
#pragma unroll
        for (int t = 0; t < 9; ++t) {
            Wf2[((t * 8 + (ci >> 3)) * 128 + co) * 8 + (ci & 7)] = f2bf(v[t] * inv);
            Wt2[((t * 16 + (co >> 3)) * 64 + ci) * 8 + (co & 7)] = f2bf(v[8 - t] * inv);
        }
    } else {
        int pb = bid - ZB_ - 32;
        int row = pb % 58, n = pb / 58;
        short* dst = Xp + ((size_t)(n * 58 + row) * 68) * 64;
        if (row >= 1 && row <= 56) {
            int h = row - 1;
            for (int j = tid; j < 64 * 56; j += 256) {
                int ci = j / 56, w = j - ci * 56;
                lx[ci * 57 + w] = x[((size_t)(n * 64 + ci)) * 3136 + h * 56 + w];
            }
            __syncthreads();
            for (int j = tid; j < 68 * 64; j += 256) {
                int s = j >> 6, ci = j & 63;
                float val = (s >= 2 && s < 58) ? lx[ci * 57 + (s - 2)] : 0.f;
                dst[(s << 6) + (ci ^ ((s & 7) << 3))] = f2bf(val);
            }
        } else {
            for (int j = tid; j < 68 * 64; j += 256) dst[j] = 0;
        }
    }
}

// ---------------------------------------------------------------------------
// conv_fwd (it0 only, mode 0): 64->128, all 128 co per block.
// Exact R1-verified kernel body. grid = 896, sid = (bid&7)*112 + bid>>3.
// ---------------------------------------------------------------------------
__global__ __launch_bounds__(256, 4) void conv_fwd(
    const short* __restrict__ inp,   // [n][58][68][64] bf16 swz (Xp)
    const short* __restrict__ Wf2,   // [9][8][128][8] bf16 k-major chunks
    short* __restrict__ Yp,          // [n][58][68][128] bf16 swz (y state)
    short* __restrict__ Cp) {        // [n][58][68][128] bf16 swz (c_prev)
    __shared__ __align__(16) short smem[14688];   // 204 rows x 72 shorts
    const int bid = blockIdx.x, tid = threadIdx.x;
    const int sid = (bid & 7) * 112 + (bid >> 3);
    const int n = sid / 56, r = sid - n * 56 + 1;
    {   // stage B: 3 input rows
        const short8* src = (const short8*)(inp + ((size_t)(n * 58 + (r - 1)) * 68) * 64);
        for (int j = tid; j < 1632; j += 256) {
            int srow = j >> 3, w = j & 7;
            *(short8*)(smem + srow * 72 + w * 8) = src[j];
        }
    }
    const int lane = tid & 63, ct = tid >> 6, quad = lane >> 4, l15 = lane & 15;
    const int cog = ct & 1, pxg = ct >> 1;
    const size_t prow = ((size_t)(n * 58 + r) * 68) * 128;
    __syncthreads();

    f32x4 acc[2][4];
#pragma unroll
    for (int pt = 0; pt < 2; ++pt)
#pragma unroll
        for (int cot = 0; cot < 4; ++cot) acc[pt][cot] = (f32x4){0.f, 0.f, 0.f, 0.f};

#pragma unroll
    for (int f = 0; f < 18; ++f) {
        const int t = f >> 1, half = f & 1;
        const int dh = t / 3, dw = t % 3;
        const int u = l15 + dw + 1;
        const int phys = (half * 4 + quad) ^ (u & 7);
        short8 areg[4];
#pragma unroll
        for (int cot = 0; cot < 4; ++cot) {
            const int co = cog * 64 + cot * 16 + l15;
            areg[cot] = *(const short8*)(Wf2 +
                ((size_t)((t * 8 + half * 4 + quad) * 128 + co)) * 8);
        }
#pragma unroll
        for (int pt = 0; pt < 2; ++pt) {
            const int pti = pxg * 2 + pt;
            const short8 bv = *(const short8*)(smem +
                (dh * 68 + pti * 16 + u) * 72 + phys * 8);
#pragma unroll
            for (int cot = 0; cot < 4; ++cot)
                acc[pt][cot] = __builtin_amdgcn_mfma_f32_16x16x32_bf16(areg[cot], bv, acc[pt][cot], 0, 0, 0);
        }
    }

    // ---- epilogue mode 0: y = cp = shrink(MU*acc), per-half bounce ----
    __syncthreads();
    short* tb_y = smem;
    short* tb_c = smem + 4608;
#pragma unroll
    for (int hh = 0; hh < 2; ++hh) {
        if (cog == hh) {
#pragma unroll
            for (int pt = 0; pt < 2; ++pt) {
                const int px = pxg * 32 + pt * 16 + l15;
#pragma unroll
                for (int cot = 0; cot < 4; ++cot) {
#pragma unroll
                    for (int reg = 0; reg < 4; ++reg) {
                        const int lch = cot * 16 + quad * 4 + reg;
                        const int slot = px * 72 + (lch ^ ((px & 3) << 3));
                        float c = fmaxf(MU_ * acc[pt][cot][reg] - THR_, 0.f);
                        short cb16 = f2bf(c);
                        tb_y[slot] = cb16;
                        tb_c[slot] = cb16;
                    }
                }
            }
        }
        __syncthreads();
        for (int item = tid; item < 448; item += 256) {
            int vv = item >> 3, g = item & 7;
            int so = vv * 72 + 8 * (g ^ (vv & 3));
            short8 yv = *(const short8*)(tb_y + so);
            short8 cv = *(const short8*)(tb_c + so);
            int s = vv + 2;
            size_t off = prow + (size_t)s * 128 + 8 * ((g + 8 * hh) ^ (s & 7));
            *(short8*)(Yp + off) = yv;
            *(short8*)(Cp + off) = cv;
        }
        if (hh == 0) __syncthreads();
    }
}

// ---------------------------------------------------------------------------
// Fused iteration: conv_t (halo recompute, rows r-1..r+1 -> LDS R-tile) then
// conv_fwd row r from the R-tile. Reads Ycur (prev dispatch), writes Ynext:
// no intra-dispatch races. R values identical bf16 bits as the old global
// Rp round-trip. mode 1: state update; mode 2: final out only.
// LDS: Ybuf[204*72] | Rtile[204*72] = 58,752 B -> 2 blocks/CU.
// ---------------------------------------------------------------------------
__global__ __launch_bounds__(256, 2) void conv_fused(
    const short* __restrict__ Ycur,  // [n][58][68][128] bf16 swz (old y)
    const short* __restrict__ Wt2,   // [9][16][64][8]
    const short* __restrict__ Wf2,   // [9][8][128][8]
    const short* __restrict__ Xp,    // [n][58][68][64]
    short* __restrict__ Ynext,       // new y (mode 1)
    short* __restrict__ Cp,          // c_prev, RW row r (mode 1)
    float* __restrict__ outp, int mode, float beta) {
    __shared__ __align__(16) short smem[29376];
    short* Ybuf  = smem;             // 14688 shorts (aliased by tb in epilogues)
    short* Rtile = smem + 14688;     // 14688 shorts: [3][68 slots][72]
    const int bid = blockIdx.x, tid = threadIdx.x;
    const int sid = (bid & 7) * 112 + (bid >> 3);
    const int n = sid / 56, r = sid - n * 56 + 1;
    const int lane = tid & 63, ct = tid >> 6, quad = lane >> 4, l15 = lane & 15;

    // zero R-tile once (pads of skipped/edge rows must read as 0)
    for (int j = tid; j < 1836; j += 256)
        ((short8*)Rtile)[j] = (short8){0, 0, 0, 0, 0, 0, 0, 0};

    // ===================== phase A: conv_t rows r-1..r+1 =====================
    for (int rr_i = 0; rr_i < 3; ++rr_i) {
        const int rr = r - 1 + rr_i;
        if (rr < 1 || rr > 56) continue;          // pad row: R stays zero
        const short8* src = (const short8*)(Ycur + ((size_t)(n * 58 + (rr - 1)) * 68) * 128);
        const size_t xrow = ((size_t)(n * 58 + rr) * 68) * 64;

        short8 xold8[2];
        int pvv[2], pg[2]; bool pok[2];
#pragma unroll
        for (int k = 0; k < 2; ++k) {
            int item = tid + k * 256;
            pok[k] = item < 448;
            pvv[k] = item >> 3; pg[k] = item & 7;
            if (pok[k]) {
                int s = pvv[k] + 2;
                xold8[k] = *(const short8*)(Xp + xrow + (size_t)s * 64 + 8 * (pg[k] ^ (s & 7)));
            }
        }

        f32x4 acc[4];
#pragma unroll
        for (int cit = 0; cit < 4; ++cit) acc[cit] = (f32x4){0.f, 0.f, 0.f, 0.f};

#pragma unroll
        for (int p = 0; p < 2; ++p) {
            __syncthreads();          // Ybuf free (prior pass reads / prior tb done)
            for (int j = tid; j < 1632; j += 256) {
                int srow = j >> 3, w = j & 7;
                *(short8*)(Ybuf + srow * 72 + w * 8) = src[srow * 16 + p * 8 + w];
            }
            __syncthreads();
#pragma unroll
            for (int f = 0; f < 18; ++f) {
                const int t = f >> 1, sh = f & 1;
                const int dh = t / 3, dw = t % 3;
                const int u = l15 + dw + 1;
                const int phys = (sh * 4 + quad) ^ (u & 7);
                short8 areg[4];
#pragma unroll
                for (int cit = 0; cit < 4; ++cit) {
                    const int ci = cit * 16 + l15;
                    areg[cit] = *(const short8*)(Wt2 +
                        ((size_t)((t * 16 + (p * 2 + sh) * 4 + quad) * 64 + ci)) * 8);
                }
                const short8 bv = *(const short8*)(Ybuf +
                    (dh * 68 + ct * 16 + u) * 72 + phys * 8);
#pragma unroll
                for (int cit = 0; cit < 4; ++cit)
                    acc[cit] = __builtin_amdgcn_mfma_f32_16x16x32_bf16(areg[cit], bv, acc[cit], 0, 0, 0);
            }
        }

        // r = x - acc via LDS bounce (tb aliases Ybuf), then into R-tile
        __syncthreads();
        short* tb = Ybuf;
#pragma unroll
        for (int k = 0; k < 2; ++k) if (pok[k]) {
            *(short8*)(tb + pvv[k] * 72 + 8 * (pg[k] ^ (pvv[k] & 3))) = xold8[k];
        }
        __syncthreads();
        {
            const int px = ct * 16 + l15;
#pragma unroll
            for (int cit = 0; cit < 4; ++cit) {
#pragma unroll
                for (int reg = 0; reg < 4; ++reg) {
                    const int cir = cit * 16 + quad * 4 + reg;
                    const int slot = px * 72 + (cir ^ ((px & 3) << 3));
                    float xo = bf2f((unsigned short)tb[slot]);
                    tb[slot] = f2bf(xo - acc[cit][reg]);
                }
            }
        }
        __syncthreads();
        for (int item = tid; item < 448; item += 256) {
            int vv = item >> 3, g = item & 7;
            short8 val = *(const short8*)(tb + vv * 72 + 8 * (g ^ (vv & 3)));
            int s = vv + 2;
            *(short8*)(Rtile + (size_t)(rr_i * 68 + s) * 72 + 8 * (g ^ (s & 7))) = val;
        }
    }

    // ===================== phase B: conv_fwd row r from R-tile ===============
    const int cog = ct & 1, pxg = ct >> 1;
    const size_t prow = ((size_t)(n * 58 + r) * 68) * 128;

    short8 yold8[2], cold8[2];
    int qvv[2], qg[2]; bool qok[2];
#pragma unroll
    for (int k = 0; k < 2; ++k) {
        int item = tid + k * 256;
        qok[k] = item < 448;
        qvv[k] = item >> 3; qg[k] = item & 7;
        if (qok[k]) {
            int s = qvv[k] + 2;
            size_t off = prow + (size_t)s * 128 + 8 * (qg[k] ^ (s & 7));
            yold8[k] = *(const short8*)(Ycur + off);
            if (mode == 1) cold8[k] = *(const short8*)(Cp + off);
        }
    }
    __syncthreads();                 // R-tile complete

    f32x4 facc[2][4];
#pragma unroll
    for (int pt = 0; pt < 2; ++pt)
#pragma unroll
        for (int cot = 0; cot < 4; ++cot) facc[pt][cot] = (f32x4){0.f, 0.f, 0.f, 0.f};

#pragma unroll
    for (int f = 0; f < 18; ++f) {
        const int t = f >> 1, half = f & 1;
        const int dh = t / 3, dw = t % 3;
        const int u = l15 + dw + 1;
        const int phys = (half * 4 + quad) ^ (u & 7);
        short8 areg[4];
#pragma unroll
        for (int cot = 0; cot < 4; ++cot) {
            const int co = cog * 64 + cot * 16 + l15;
            areg[cot] = *(const short8*)(Wf2 +
                ((size_t)((t * 8 + half * 4 + quad) * 128 + co)) * 8);
        }
#pragma unroll
        for (int pt = 0; pt < 2; ++pt) {
            const int pti = pxg * 2 + pt;
            const short8 bv = *(const short8*)(Rtile +
                (dh * 68 + pti * 16 + u) * 72 + phys * 8);
#pragma unroll
            for (int cot = 0; cot < 4; ++cot)
                facc[pt][cot] = __builtin_amdgcn_mfma_f32_16x16x32_bf16(areg[cot], bv, facc[pt][cot], 0, 0, 0);
        }
    }

    // ---- epilogue: per-half state bounce via LDS (Ybuf dead) ----
    __syncthreads();
    short* tb_y = Ybuf;
    short* tb_c = Ybuf + 4608;
    const int h = r - 1;
#pragma unroll
    for (int hh = 0; hh < 2; ++hh) {
#pragma unroll
        for (int k = 0; k < 2; ++k) if (qok[k]) {
            int o = qvv[k] * 72 + 8 * (qg[k] ^ (qvv[k] & 3));
            *(short8*)(tb_y + o) = yold8[k];
            if (mode == 1) *(short8*)(tb_c + o) = cold8[k];
        }
        __syncthreads();
        // issue half-1 loads early; latency hides under half-0 processing
        if (hh == 0) {
#pragma unroll
            for (int k = 0; k < 2; ++k) if (qok[k]) {
                int s = qvv[k] + 2;
                size_t off = prow + (size_t)s * 128 + 8 * ((qg[k] + 8) ^ (s & 7));
                yold8[k] = *(const short8*)(Ycur + off);
                if (mode == 1) cold8[k] = *(const short8*)(Cp + off);
            }
        }
        if (cog == hh) {
#pragma unroll
            for (int pt = 0; pt < 2; ++pt) {
                const int px = pxg * 32 + pt * 16 + l15;
#pragma unroll
                for (int cot = 0; cot < 4; ++cot) {
#pragma unroll
                    for (int reg = 0; reg < 4; ++reg) {
                        const int lch = cot * 16 + quad * 4 + reg;
                        const int slot = px * 72 + (lch ^ ((px & 3) << 3));
                        const float a = facc[pt][cot][reg];
                        if (mode == 1) {
                            float yold = bf2f((unsigned short)tb_y[slot]);
                            float cold = bf2f((unsigned short)tb_c[slot]);
                            float c = fmaxf(yold + MU_ * a - THR_, 0.f);
                            tb_y[slot] = f2bf(c + beta * (c - cold));
                            tb_c[slot] = f2bf(c);
                        } else {
                            if (px < 56) {
                                float yold = bf2f((unsigned short)tb_y[slot]);
                                float c = fmaxf(yold + MU_ * a - THR_, 0.f);
                                outp[((size_t)(n * 128 + hh * 64 + lch)) * 3136 + h * 56 + px] = c;
                            }
                        }
                    }
                }
            }
        }
        if (mode == 1) {
            __syncthreads();
            for (int item = tid; item < 448; item += 256) {
                int vv = item >> 3, g = item & 7;
                int so = vv * 72 + 8 * (g ^ (vv & 3));
                short8 yv = *(const short8*)(tb_y + so);
                short8 cv = *(const short8*)(tb_c + so);
                int s = vv + 2;
                size_t off = prow + (size_t)s * 128 + 8 * ((g + 8 * hh) ^ (s & 7));
                *(short8*)(Ynext + off) = yv;
                *(short8*)(Cp + off) = cv;
            }
        }
        if (hh == 0) __syncthreads();
    }
}

// ---------------------------------------------------------------------------
extern "C" void kernel_launch(void* const* d_in, const int* in_sizes, int n_in,
                              void* d_out, int out_size, void* d_ws, size_t ws_size,
                              hipStream_t stream) {
    const float* x = (const float*)d_in[0];   // [16,64,56,56] fp32
    const float* W = (const float*)d_in[1];   // [128,64,3,3]  fp32
    float* out = (float*)d_out;               // [16,128,56,56] fp32

    // ws layout (all bf16): Xp | YA | YB | Cp | Wf2 | Wt2  (~57 MB)
    const size_t XPN = (size_t)16 * 58 * 68 * 64;   // 4,038,656
    const size_t YPN = 2 * XPN;                      // 8,077,312
    short* Xp = (short*)d_ws;
    short* YA = Xp + XPN;
    short* YB = YA + YPN;
    short* Cp = YB + YPN;
    short* Wf2 = Cp + YPN;                // 73728 shorts
    short* Wt2 = Wf2 + 73728;             // 73728 shorts

    const int n4 = (int)(2 * YPN * 2 / 16);         // 2,019,328 (ZB_=7888)
    const int prep_blocks = ZB_ + 32 + 58 * 16;     // 8848
    hipLaunchKernelGGL(prep_kernel, dim3(prep_blocks), dim3(256), 0, stream,
                       x, W, (float4*)YA, n4, Xp, Wf2, Wt2);

    dim3 b(256, 1, 1);
    // it0: c = shrink(MU * conv(x)); y = cp = c  -> YA, Cp
    hipLaunchKernelGGL(conv_fwd, dim3(896), b, 0, stream, Xp, Wf2, YA, Cp);
    double t = 1.0;
    for (int it = 1; it <= 5; ++it) {
        double tn = (1.0 + sqrt(1.0 + 4.0 * t * t)) / 2.0;
        float beta = (float)((t - 1.0) / tn);
        short* Ycur  = (it & 1) ? YA : YB;
        short* Ynext = (it & 1) ? YB : YA;
        hipLaunchKernelGGL(conv_fused, dim3(896), b, 0, stream,
                           Ycur, Wt2, Wf2, Xp, Ynext, Cp,
                           (it == 5) ? out : (float*)nullptr,
                           (it == 5) ? 2 : 1, beta);
        t = tn;
    }
}

// Round 4
// 352.174 us; speedup vs baseline: 14.2250x; 3.5761x over previous
//
#include <hip/hip_runtime.h>
#include <hip/hip_bf16.h>
#include <math.h>

typedef __attribute__((ext_vector_type(8))) short short8;
typedef __attribute__((ext_vector_type(4))) float f32x4;

#define MU_  0.1f
#define THR_ 0.01f
#define ZB_  204   // zero blocks: pad rows 0,57 of Rp+Yp = 52,224 short8 / 256

static __device__ inline short f2bf(float f) {
    __hip_bfloat16 h = __float2bfloat16(f);
    return *reinterpret_cast<short*>(&h);
}
static __device__ inline float bf2f(unsigned short u) {
    unsigned int x = ((unsigned int)u) << 16;
    return __builtin_bit_cast(float, x);
}

// ---------------------------------------------------------------------------
// Merged prep: [0,ZB_) zero pad ROWS (0,57) of Rp+Yp only (pad columns are
// never read from global anymore — staging is interior-only and kernels
// LDS-memset pad slots); [ZB_,ZB_+32) wnorm; rest pack_x.
//  Wf2[t][ci>>3][co][ci&7] = Wn[co][ci*9+t]        (fwd A, k-major chunks)
//  Wt2[t][co>>3][ci][co&7] = Wn[co][ci*9+(8-t)]    (conv_t A, k-major chunks)
// ---------------------------------------------------------------------------
__global__ __launch_bounds__(256) void prep_kernel(
    const float* __restrict__ x, const float* __restrict__ W,
    short* __restrict__ Rp, short* __restrict__ Yp,
    short* __restrict__ Xp, short* __restrict__ Wf2, short* __restrict__ Wt2) {
    __shared__ float lx[64 * 57];
    const int bid = blockIdx.x, tid = threadIdx.x;
    if (bid < ZB_) {
        int gid = bid * 256 + tid;          // [0, 52224)
        const short8 z = {0, 0, 0, 0, 0, 0, 0, 0};
        if (gid < 17408) {                  // Rp pad rows: 32 rows x 544 short8
            int ridx = gid / 544, off = gid - ridx * 544;
            int n = ridx >> 1, row = (ridx & 1) * 57;
            ((short8*)(Rp + ((size_t)(n * 58 + row) * 68) * 64))[off] = z;
        } else {                            // Yp pad rows: 32 rows x 1088 short8
            int g2 = gid - 17408;
            int ridx = g2 / 1088, off = g2 - ridx * 1088;
            int n = ridx >> 1, row = (ridx & 1) * 57;
            ((short8*)(Yp + ((size_t)(n * 58 + row) * 68) * 128))[off] = z;
        }
    } else if (bid < ZB_ + 32) {
        int co = (bid - ZB_) * 4 + (tid >> 6);
        int ci = tid & 63;
        const float* wp = W + (co * 64 + ci) * 9;
        float v[9]; float s = 0.f;
#pragma unroll
        for (int t = 0; t < 9; ++t) { v[t] = wp[t]; s += v[t] * v[t]; }
#pragma unroll
        for (int off = 32; off; off >>= 1) s += __shfl_xor(s, off, 64);
        float inv = 1.0f / sqrtf(s + 1e-12f);
#pragma unroll
        for (int t = 0; t < 9; ++t) {
            Wf2[((t * 8 + (ci >> 3)) * 128 + co) * 8 + (ci & 7)] = f2bf(v[t] * inv);
            Wt2[((t * 16 + (co >> 3)) * 64 + ci) * 8 + (co & 7)] = f2bf(v[8 - t] * inv);
        }
    } else {
        int pb = bid - ZB_ - 32;
        int row = pb % 58, n = pb / 58;
        short* dst = Xp + ((size_t)(n * 58 + row) * 68) * 64;
        if (row >= 1 && row <= 56) {
            int h = row - 1;
            for (int j = tid; j < 64 * 56; j += 256) {
                int ci = j / 56, w = j - ci * 56;
                lx[ci * 57 + w] = x[((size_t)(n * 64 + ci)) * 3136 + h * 56 + w];
            }
            __syncthreads();
            for (int j = tid; j < 68 * 64; j += 256) {
                int s = j >> 6, ci = j & 63;
                float val = (s >= 2 && s < 58) ? lx[ci * 57 + (s - 2)] : 0.f;
                dst[(s << 6) + (ci ^ ((s & 7) << 3))] = f2bf(val);
            }
        } else {
            for (int j = tid; j < 68 * 64; j += 256) dst[j] = 0;
        }
    }
}

// LDS pad-slot zeroing: slots {0,1,58..67} of the 3 row-buffers, shorts 0..63.
// 36 slot-rows x 8 short8 = 288 items. Disjoint from staged slots [2,58).
static __device__ __forceinline__ void zero_lds_pads(short* smem, int tid) {
    const short8 z = {0, 0, 0, 0, 0, 0, 0, 0};
    for (int i = tid; i < 288; i += 256) {
        int sr = i >> 3, w = i & 7;
        int row = sr / 12, sl = sr - row * 12;
        int s = (sl < 2) ? sl : sl + 56;
        *(short8*)(smem + (row * 68 + s) * 72 + w * 8) = z;
    }
}

// ---------------------------------------------------------------------------
// Forward conv 64->128, 16x16x32 MFMA. One block per output row, all 128 co.
// Waves 2x2: cog = ct&1 (64 co), pxg = ct>>1 (32 px). Interior-only staging
// (slots 2..57), LDS pads memset. grid = 896, sid = (bid&7)*112 + bid>>3.
// mode 0: c=shrink(MU*acc); y=cp=c
// mode 1: c=shrink(y_old+MU*acc); y=c+beta*(c-cp_old); cp=c
// mode 2: out=shrink(y_old+MU*acc) (fp32 NCHW, no state writes)
// ---------------------------------------------------------------------------
__global__ __launch_bounds__(256, 4) void conv_fwd(
    const short* __restrict__ inp,   // [n][58][68][64] bf16 swz (Xp or Rp)
    const short* __restrict__ Wf2,   // [9][8][128][8] bf16 k-major chunks
    short* __restrict__ Yp,          // [n][58][68][128] bf16 swz (y state)
    short* __restrict__ Cp,          // [n][58][68][128] bf16 swz (c_prev)
    float* __restrict__ outp, int mode, float beta) {
    __shared__ __align__(16) short smem[14688];   // 204 rows x 72 shorts
    const int bid = blockIdx.x, tid = threadIdx.x;
    const int sid = (bid & 7) * 112 + (bid >> 3);
    const int n = sid / 56, r = sid - n * 56 + 1;
    zero_lds_pads(smem, tid);
    {   // stage B: 3 input rows, interior slots only (1344 short8 items)
        const short8* src = (const short8*)(inp + ((size_t)(n * 58 + (r - 1)) * 68) * 64);
        for (int j = tid; j < 1344; j += 256) {
            int sr = j >> 3, w = j & 7;
            int row = sr / 56, s = sr - row * 56 + 2;
            *(short8*)(smem + (row * 68 + s) * 72 + w * 8) = src[(row * 68 + s) * 8 + w];
        }
    }
    const int lane = tid & 63, ct = tid >> 6, quad = lane >> 4, l15 = lane & 15;
    const int cog = ct & 1, pxg = ct >> 1;
    const size_t prow = ((size_t)(n * 58 + r) * 68) * 128;

    // pre-loop coalesced prefetch of half-0 old y / c_prev (448 short8 items)
    short8 yold8[2], cold8[2];
    int pvv[2], pg[2]; bool pok[2];
#pragma unroll
    for (int k = 0; k < 2; ++k) {
        int item = tid + k * 256;
        pok[k] = item < 448;
        pvv[k] = item >> 3; pg[k] = item & 7;
        if (mode != 0 && pok[k]) {
            int s = pvv[k] + 2;
            size_t off = prow + (size_t)s * 128 + 8 * (pg[k] ^ (s & 7));
            yold8[k] = *(const short8*)(Yp + off);
            if (mode == 1) cold8[k] = *(const short8*)(Cp + off);
        }
    }
    __syncthreads();

    f32x4 acc[2][4];
#pragma unroll
    for (int pt = 0; pt < 2; ++pt)
#pragma unroll
        for (int cot = 0; cot < 4; ++cot) acc[pt][cot] = (f32x4){0.f, 0.f, 0.f, 0.f};

#pragma unroll
    for (int f = 0; f < 18; ++f) {            // 18 k-frags, A streamed
        const int t = f >> 1, half = f & 1;
        const int dh = t / 3, dw = t % 3;
        const int u = l15 + dw + 1;
        const int phys = (half * 4 + quad) ^ (u & 7);
        short8 areg[4];
#pragma unroll
        for (int cot = 0; cot < 4; ++cot) {
            const int co = cog * 64 + cot * 16 + l15;
            areg[cot] = *(const short8*)(Wf2 +
                ((size_t)((t * 8 + half * 4 + quad) * 128 + co)) * 8);
        }
#pragma unroll
        for (int pt = 0; pt < 2; ++pt) {
            const int pti = pxg * 2 + pt;
            const short8 bv = *(const short8*)(smem +
                (dh * 68 + pti * 16 + u) * 72 + phys * 8);
#pragma unroll
            for (int cot = 0; cot < 4; ++cot)
                acc[pt][cot] = __builtin_amdgcn_mfma_f32_16x16x32_bf16(areg[cot], bv, acc[pt][cot], 0, 0, 0);
        }
    }

    // ---- epilogue: per-half state bounce via LDS (smem dead) ----
    __syncthreads();
    short* tb_y = smem;              // [64 px][72 ch-half]
    short* tb_c = smem + 4608;
    const int h = r - 1;
#pragma unroll
    for (int hh = 0; hh < 2; ++hh) {
        if (mode != 0) {
#pragma unroll
            for (int k = 0; k < 2; ++k) if (pok[k]) {
                int o = pvv[k] * 72 + 8 * (pg[k] ^ (pvv[k] & 3));
                *(short8*)(tb_y + o) = yold8[k];
                if (mode == 1) *(short8*)(tb_c + o) = cold8[k];
            }
        }
        __syncthreads();
        // issue half-1 loads early; latency hides under half-0 processing
        if (hh == 0 && mode != 0) {
#pragma unroll
            for (int k = 0; k < 2; ++k) if (pok[k]) {
                int s = pvv[k] + 2;
                size_t off = prow + (size_t)s * 128 + 8 * ((pg[k] + 8) ^ (s & 7));
                yold8[k] = *(const short8*)(Yp + off);
                if (mode == 1) cold8[k] = *(const short8*)(Cp + off);
            }
        }
        if (cog == hh) {
#pragma unroll
            for (int pt = 0; pt < 2; ++pt) {
                const int px = pxg * 32 + pt * 16 + l15;
#pragma unroll
                for (int cot = 0; cot < 4; ++cot) {
#pragma unroll
                    for (int reg = 0; reg < 4; ++reg) {
                        const int lch = cot * 16 + quad * 4 + reg;   // 0..63
                        const int slot = px * 72 + (lch ^ ((px & 3) << 3));
                        const float a = acc[pt][cot][reg];
                        if (mode == 0) {
                            float c = fmaxf(MU_ * a - THR_, 0.f);
                            short cb16 = f2bf(c);
                            tb_y[slot] = cb16;
                            tb_c[slot] = cb16;
                        } else if (mode == 1) {
                            float yold = bf2f((unsigned short)tb_y[slot]);
                            float cold = bf2f((unsigned short)tb_c[slot]);
                            float c = fmaxf(yold + MU_ * a - THR_, 0.f);
                            tb_y[slot] = f2bf(c + beta * (c - cold));
                            tb_c[slot] = f2bf(c);
                        } else {
                            if (px < 56) {
                                float yold = bf2f((unsigned short)tb_y[slot]);
                                float c = fmaxf(yold + MU_ * a - THR_, 0.f);
                                outp[((size_t)(n * 128 + hh * 64 + lch)) * 3136 + h * 56 + px] = c;
                            }
                        }
                    }
                }
            }
        }
        if (mode != 2) {
            __syncthreads();
            for (int item = tid; item < 448; item += 256) {
                int vv = item >> 3, g = item & 7;
                int so = vv * 72 + 8 * (g ^ (vv & 3));
                short8 yv = *(const short8*)(tb_y + so);
                short8 cv = *(const short8*)(tb_c + so);
                int s = vv + 2;
                size_t off = prow + (size_t)s * 128 + 8 * ((g + 8 * hh) ^ (s & 7));
                *(short8*)(Yp + off) = yv;
                *(short8*)(Cp + off) = cv;
            }
        }
        if (hh == 0) __syncthreads();   // tables free before half-1 reuse
    }
}

// ---------------------------------------------------------------------------
// Transpose conv 128->64, 16x16x32 MFMA. Wave = 64 ci x 16 px. 2 LDS passes
// over K chunk halves; pass-1 staging register-prefetched during pass-0
// compute (T14). Interior-only staging + LDS pad memset. Fused r = x - D^T y.
// grid = 896, sid = (bid&7)*112 + bid>>3.
// ---------------------------------------------------------------------------
__global__ __launch_bounds__(256, 4) void conv_t(
    const short* __restrict__ Ypb,   // [n][58][68][128] bf16 swz
    const short* __restrict__ Wt2,   // [9][16][64][8] bf16 k-major chunks
    const short* __restrict__ Xp,    // [n][58][68][64] bf16 swz
    short* __restrict__ Rp) {        // [n][58][68][64] bf16 swz
    __shared__ __align__(16) short smem[14688];   // 204 rows x 72 shorts
    const int bid = blockIdx.x, tid = threadIdx.x;
    const int sid = (bid & 7) * 112 + (bid >> 3);
    const int n = sid / 56, r = sid - n * 56 + 1;
    const int lane = tid & 63, ct = tid >> 6, quad = lane >> 4, l15 = lane & 15;
    const short8* src = (const short8*)(Ypb + ((size_t)(n * 58 + (r - 1)) * 68) * 128);
    const size_t prow = ((size_t)(n * 58 + r) * 68) * 64;

    // pre-loop coalesced prefetch of x row (448 short8 items)
    short8 xold8[2];
    int pvv[2], pg[2]; bool pok[2];
#pragma unroll
    for (int k = 0; k < 2; ++k) {
        int item = tid + k * 256;
        pok[k] = item < 448;
        pvv[k] = item >> 3; pg[k] = item & 7;
        if (pok[k]) {
            int s = pvv[k] + 2;
            xold8[k] = *(const short8*)(Xp + prow + (size_t)s * 64 + 8 * (pg[k] ^ (s & 7)));
        }
    }

    zero_lds_pads(smem, tid);
    // stage pass-0 (chunk half 0), interior slots only
    for (int j = tid; j < 1344; j += 256) {
        int sr = j >> 3, w = j & 7;
        int row = sr / 56, s = sr - row * 56 + 2;
        *(short8*)(smem + (row * 68 + s) * 72 + w * 8) = src[(row * 68 + s) * 16 + w];
    }

    f32x4 acc[4];                     // [cit] : 64 ci per wave, 16 px
#pragma unroll
    for (int cit = 0; cit < 4; ++cit) acc[cit] = (f32x4){0.f, 0.f, 0.f, 0.f};

    __syncthreads();

    // T14: issue pass-1 staging loads now; latency hides under pass-0 compute
    short8 pf[6];
#pragma unroll
    for (int k = 0; k < 6; ++k) {
        int j = tid + k * 256;
        if (j < 1344) {
            int sr = j >> 3, w = j & 7;
            int row = sr / 56, s = sr - row * 56 + 2;
            pf[k] = src[(row * 68 + s) * 16 + 8 + w];
        }
    }

#pragma unroll
    for (int p = 0; p < 2; ++p) {
        if (p) {
            __syncthreads();          // pass-0 B reads complete
            // write prefetched pass-1 tile
#pragma unroll
            for (int k = 0; k < 6; ++k) {
                int j = tid + k * 256;
                if (j < 1344) {
                    int sr = j >> 3, w = j & 7;
                    int row = sr / 56, s = sr - row * 56 + 2;
                    *(short8*)(smem + (row * 68 + s) * 72 + w * 8) = pf[k];
                }
            }
            __syncthreads();
        }
#pragma unroll
        for (int f = 0; f < 18; ++f) {         // 18 k-frags this pass
            const int t = f >> 1, sh = f & 1;
            const int dh = t / 3, dw = t % 3;
            const int u = l15 + dw + 1;
            const int phys = (sh * 4 + quad) ^ (u & 7);
            short8 areg[4];
#pragma unroll
            for (int cit = 0; cit < 4; ++cit) {
                const int ci = cit * 16 + l15;
                areg[cit] = *(const short8*)(Wt2 +
                    ((size_t)((t * 16 + (p * 2 + sh) * 4 + quad) * 64 + ci)) * 8);
            }
            const short8 bv = *(const short8*)(smem +
                (dh * 68 + ct * 16 + u) * 72 + phys * 8);
#pragma unroll
            for (int cit = 0; cit < 4; ++cit)
                acc[cit] = __builtin_amdgcn_mfma_f32_16x16x32_bf16(areg[cit], bv, acc[cit], 0, 0, 0);
        }
    }

    // ---- epilogue: r = x - acc via LDS bounce ----
    __syncthreads();
    short* tb = smem;                // [64 px][72 ch]
#pragma unroll
    for (int k = 0; k < 2; ++k) if (pok[k]) {
        *(short8*)(tb + pvv[k] * 72 + 8 * (pg[k] ^ (pvv[k] & 3))) = xold8[k];
    }
    __syncthreads();
    {
        const int px = ct * 16 + l15;
#pragma unroll
        for (int cit = 0; cit < 4; ++cit) {
#pragma unroll
            for (int reg = 0; reg < 4; ++reg) {
                const int cir = cit * 16 + quad * 4 + reg;
                const int slot = px * 72 + (cir ^ ((px & 3) << 3));
                float xo = bf2f((unsigned short)tb[slot]);
                tb[slot] = f2bf(xo - acc[cit][reg]);
            }
        }
    }
    __syncthreads();
    for (int item = tid; item < 448; item += 256) {
        int vv = item >> 3, g = item & 7;
        short8 val = *(const short8*)(tb + vv * 72 + 8 * (g ^ (vv & 3)));
        int s = vv + 2;
        *(short8*)(Rp + prow + (size_t)s * 64 + 8 * (g ^ (s & 7))) = val;
    }
}

// ---------------------------------------------------------------------------
extern "C" void kernel_launch(void* const* d_in, const int* in_sizes, int n_in,
                              void* d_out, int out_size, void* d_ws, size_t ws_size,
                              hipStream_t stream) {
    const float* x = (const float*)d_in[0];   // [16,64,56,56] fp32
    const float* W = (const float*)d_in[1];   // [128,64,3,3]  fp32
    float* out = (float*)d_out;               // [16,128,56,56] fp32

    // ws layout (all bf16): Xp | Rp | Yp | Cp | Wf2 | Wt2  (~49 MB)
    const size_t XPN = (size_t)16 * 58 * 68 * 64;   // 4,038,656
    const size_t YPN = 2 * XPN;                      // 8,077,312
    short* Xp = (short*)d_ws;
    short* Rp = Xp + XPN;
    short* Yp = Rp + XPN;
    short* Cp = Yp + YPN;
    short* Wf2 = Cp + YPN;                // 73728 shorts
    short* Wt2 = Wf2 + 73728;             // 73728 shorts

    const int prep_blocks = ZB_ + 32 + 58 * 16;     // 1164
    hipLaunchKernelGGL(prep_kernel, dim3(prep_blocks), dim3(256), 0, stream,
                       x, W, Rp, Yp, Xp, Wf2, Wt2);

    dim3 b(256, 1, 1);
    // it0: c = shrink(MU * conv(x)); y = cp = c
    hipLaunchKernelGGL(conv_fwd, dim3(896), b, 0, stream, Xp, Wf2, Yp, Cp,
                       (float*)nullptr, 0, 0.f);
    double t = 1.0;
    for (int it = 1; it <= 5; ++it) {
        hipLaunchKernelGGL(conv_t, dim3(896), b, 0, stream, Yp, Wt2, Xp, Rp);
        double tn = (1.0 + sqrt(1.0 + 4.0 * t * t)) / 2.0;
        float beta = (float)((t - 1.0) / tn);
        hipLaunchKernelGGL(conv_fwd, dim3(896), b, 0, stream, Rp, Wf2, Yp, Cp,
                           (it == 5) ? out : (float*)nullptr, (it == 5) ? 2 : 1,
                           beta);
        t = tn;
    }
}

// Round 5
// 344.381 us; speedup vs baseline: 14.5469x; 1.0226x over previous
//
#include <hip/hip_runtime.h>
#include <hip/hip_bf16.h>
#include <math.h>

typedef __attribute__((ext_vector_type(8))) short short8;
typedef __attribute__((ext_vector_type(4))) float f32x4;

#define MU_  0.1f
#define THR_ 0.01f
#define ZB_  204   // zero blocks: pad rows 0,57 of Rp+Yp = 52,224 short8 / 256

static __device__ inline short f2bf(float f) {
    __hip_bfloat16 h = __float2bfloat16(f);
    return *reinterpret_cast<short*>(&h);
}
static __device__ inline float bf2f(unsigned short u) {
    unsigned int x = ((unsigned int)u) << 16;
    return __builtin_bit_cast(float, x);
}

// ---------------------------------------------------------------------------
// Merged prep: [0,ZB_) zero pad ROWS (0,57) of Rp+Yp only; [ZB_,ZB_+32) wnorm;
// rest pack_x. (Pad columns never read from global — staging is interior-only
// and conv kernels LDS-memset pad slots.)
//  Wf2[t][ci>>3][co][ci&7] = Wn[co][ci*9+t]        (fwd A, k-major chunks)
//  Wt2[t][co>>3][ci][co&7] = Wn[co][ci*9+(8-t)]    (conv_t A, k-major chunks)
// ---------------------------------------------------------------------------
__global__ __launch_bounds__(256) void prep_kernel(
    const float* __restrict__ x, const float* __restrict__ W,
    short* __restrict__ Rp, short* __restrict__ Yp,
    short* __restrict__ Xp, short* __restrict__ Wf2, short* __restrict__ Wt2) {
    __shared__ float lx[64 * 57];
    const int bid = blockIdx.x, tid = threadIdx.x;
    if (bid < ZB_) {
        int gid = bid * 256 + tid;          // [0, 52224)
        const short8 z = {0, 0, 0, 0, 0, 0, 0, 0};
        if (gid < 17408) {                  // Rp pad rows: 32 rows x 544 short8
            int ridx = gid / 544, off = gid - ridx * 544;
            int n = ridx >> 1, row = (ridx & 1) * 57;
            ((short8*)(Rp + ((size_t)(n * 58 + row) * 68) * 64))[off] = z;
        } else {                            // Yp pad rows: 32 rows x 1088 short8
            int g2 = gid - 17408;
            int ridx = g2 / 1088, off = g2 - ridx * 1088;
            int n = ridx >> 1, row = (ridx & 1) * 57;
            ((short8*)(Yp + ((size_t)(n * 58 + row) * 68) * 128))[off] = z;
        }
    } else if (bid < ZB_ + 32) {
        int co = (bid - ZB_) * 4 + (tid >> 6);
        int ci = tid & 63;
        const float* wp = W + (co * 64 + ci) * 9;
        float v[9]; float s = 0.f;
#pragma unroll
        for (int t = 0; t < 9; ++t) { v[t] = wp[t]; s += v[t] * v[t]; }
#pragma unroll
        for (int off = 32; off; off >>= 1) s += __shfl_xor(s, off, 64);
        float inv = 1.0f / sqrtf(s + 1e-12f);
#pragma unroll
        for (int t = 0; t < 9; ++t) {
            Wf2[((t * 8 + (ci >> 3)) * 128 + co) * 8 + (ci & 7)] = f2bf(v[t] * inv);
            Wt2[((t * 16 + (co >> 3)) * 64 + ci) * 8 + (co & 7)] = f2bf(v[8 - t] * inv);
        }
    } else {
        int pb = bid - ZB_ - 32;
        int row = pb % 58, n = pb / 58;
        short* dst = Xp + ((size_t)(n * 58 + row) * 68) * 64;
        if (row >= 1 && row <= 56) {
            int h = row - 1;
            for (int j = tid; j < 64 * 56; j += 256) {
                int ci = j / 56, w = j - ci * 56;
                lx[ci * 57 + w] = x[((size_t)(n * 64 + ci)) * 3136 + h * 56 + w];
            }
            __syncthreads();
            for (int j = tid; j < 68 * 64; j += 256) {
                int s = j >> 6, ci = j & 63;
                float val = (s >= 2 && s < 58) ? lx[ci * 57 + (s - 2)] : 0.f;
                dst[(s << 6) + (ci ^ ((s & 7) << 3))] = f2bf(val);
            }
        } else {
            for (int j = tid; j < 68 * 64; j += 256) dst[j] = 0;
        }
    }
}

// LDS pad-slot zeroing for a 4-row window: slots {0,1,58..67}, shorts 0..63.
// 4 rows x 12 slots x 8 short8 = 384 items. Disjoint from staged slots [2,58).
static __device__ __forceinline__ void zero_lds_pads4(short* smem, int tid) {
    const short8 z = {0, 0, 0, 0, 0, 0, 0, 0};
    for (int i = tid; i < 384; i += 256) {
        int sr = i >> 3, w = i & 7;
        int row = sr / 12, sl = sr - row * 12;
        int s = (sl < 2) ? sl : sl + 56;
        *(short8*)(smem + (row * 68 + s) * 72 + w * 8) = z;
    }
}

// ---------------------------------------------------------------------------
// Forward conv 64->128, row-PAIR blocks: each block computes rows r0,r0+1
// (all 128 co) from a shared 4-row staged window. grid = 448:
// sid0 = (bid&7)*112 + (bid>>3)*2 (XCD-local, pairs never straddle images).
// Waves 2x2: cog = ct&1 (64 co), pxg = ct>>1 (32 px); acc[2 rows][2 pt][4 cot].
// LDS: 4x68x72 staging (19584 sh) + 4 tables (18432 sh) = 76 KB, 2 blocks/CU.
// mode 0: c=shrink(MU*acc); y=cp=c
// mode 1: c=shrink(y_old+MU*acc); y=c+beta*(c-cp_old); cp=c
// mode 2: out=shrink(y_old+MU*acc) (fp32 NCHW, no state writes)
// ---------------------------------------------------------------------------
__global__ __launch_bounds__(256, 2) void conv_fwd(
    const short* __restrict__ inp,   // [n][58][68][64] bf16 swz (Xp or Rp)
    const short* __restrict__ Wf2,   // [9][8][128][8] bf16 k-major chunks
    short* __restrict__ Yp,          // [n][58][68][128] bf16 swz (y state)
    short* __restrict__ Cp,          // [n][58][68][128] bf16 swz (c_prev)
    float* __restrict__ outp, int mode, float beta) {
    __shared__ __align__(16) short smem[38016];
    const int bid = blockIdx.x, tid = threadIdx.x;
    const int sid0 = (bid & 7) * 112 + (bid >> 3) * 2;
    const int n = sid0 / 56, r0 = sid0 - n * 56 + 1;
    zero_lds_pads4(smem, tid);
    {   // stage 4 input rows r0-1..r0+2, interior slots (1792 short8 items)
        const short8* src = (const short8*)(inp + ((size_t)(n * 58 + (r0 - 1)) * 68) * 64);
        for (int j = tid; j < 1792; j += 256) {
            int sr = j >> 3, w = j & 7;
            int row = sr / 56, s = sr - row * 56 + 2;
            *(short8*)(smem + (row * 68 + s) * 72 + w * 8) = src[(row * 68 + s) * 8 + w];
        }
    }
    const int lane = tid & 63, ct = tid >> 6, quad = lane >> 4, l15 = lane & 15;
    const int cog = ct & 1, pxg = ct >> 1;
    size_t prow[2];
    prow[0] = ((size_t)(n * 58 + r0) * 68) * 128;
    prow[1] = prow[0] + 68 * 128;

    // pre-loop coalesced prefetch of half-0 old y / c_prev for BOTH rows
    short8 yold8[2][2], cold8[2][2];
    int pvv[2], pg[2]; bool pok[2];
#pragma unroll
    for (int k = 0; k < 2; ++k) {
        int item = tid + k * 256;
        pok[k] = item < 448;
        pvv[k] = item >> 3; pg[k] = item & 7;
        if (mode != 0 && pok[k]) {
            int s = pvv[k] + 2;
            int xo = 8 * (pg[k] ^ (s & 7));
#pragma unroll
            for (int rw = 0; rw < 2; ++rw) {
                size_t off = prow[rw] + (size_t)s * 128 + xo;
                yold8[rw][k] = *(const short8*)(Yp + off);
                if (mode == 1) cold8[rw][k] = *(const short8*)(Cp + off);
            }
        }
    }
    __syncthreads();

    f32x4 acc[2][2][4];
#pragma unroll
    for (int rw = 0; rw < 2; ++rw)
#pragma unroll
        for (int pt = 0; pt < 2; ++pt)
#pragma unroll
            for (int cot = 0; cot < 4; ++cot) acc[rw][pt][cot] = (f32x4){0.f, 0.f, 0.f, 0.f};

#pragma unroll
    for (int f = 0; f < 18; ++f) {            // 18 k-frags; A shared by rows
        const int t = f >> 1, half = f & 1;
        const int dh = t / 3, dw = t % 3;
        const int u = l15 + dw + 1;
        const int phys = (half * 4 + quad) ^ (u & 7);
        short8 areg[4];
#pragma unroll
        for (int cot = 0; cot < 4; ++cot) {
            const int co = cog * 64 + cot * 16 + l15;
            areg[cot] = *(const short8*)(Wf2 +
                ((size_t)((t * 8 + half * 4 + quad) * 128 + co)) * 8);
        }
#pragma unroll
        for (int rw = 0; rw < 2; ++rw) {
#pragma unroll
            for (int pt = 0; pt < 2; ++pt) {
                const int pti = pxg * 2 + pt;
                const short8 bv = *(const short8*)(smem +
                    ((dh + rw) * 68 + pti * 16 + u) * 72 + phys * 8);
#pragma unroll
                for (int cot = 0; cot < 4; ++cot)
                    acc[rw][pt][cot] = __builtin_amdgcn_mfma_f32_16x16x32_bf16(areg[cot], bv, acc[rw][pt][cot], 0, 0, 0);
            }
        }
    }

    // ---- epilogue: per-half state bounce, tables separate from staging ----
    short* tbase = smem + 19584;     // [rw][y|c][64 px][72 ch-half]
    const int h0 = r0 - 1;
#pragma unroll
    for (int hh = 0; hh < 2; ++hh) {
        if (mode != 0) {
#pragma unroll
            for (int rw = 0; rw < 2; ++rw) {
                short* tb_y = tbase + rw * 9216;
                short* tb_c = tb_y + 4608;
#pragma unroll
                for (int k = 0; k < 2; ++k) if (pok[k]) {
                    int o = pvv[k] * 72 + 8 * (pg[k] ^ (pvv[k] & 3));
                    *(short8*)(tb_y + o) = yold8[rw][k];
                    if (mode == 1) *(short8*)(tb_c + o) = cold8[rw][k];
                }
            }
        }
        __syncthreads();
        // issue half-1 loads early; latency hides under half-0 processing
        if (hh == 0 && mode != 0) {
#pragma unroll
            for (int k = 0; k < 2; ++k) if (pok[k]) {
                int s = pvv[k] + 2;
                int xo = 8 * ((pg[k] + 8) ^ (s & 7));
#pragma unroll
                for (int rw = 0; rw < 2; ++rw) {
                    size_t off = prow[rw] + (size_t)s * 128 + xo;
                    yold8[rw][k] = *(const short8*)(Yp + off);
                    if (mode == 1) cold8[rw][k] = *(const short8*)(Cp + off);
                }
            }
        }
        if (cog == hh) {
#pragma unroll
            for (int rw = 0; rw < 2; ++rw) {
                short* tb_y = tbase + rw * 9216;
                short* tb_c = tb_y + 4608;
#pragma unroll
                for (int pt = 0; pt < 2; ++pt) {
                    const int px = pxg * 32 + pt * 16 + l15;
#pragma unroll
                    for (int cot = 0; cot < 4; ++cot) {
#pragma unroll
                        for (int reg = 0; reg < 4; ++reg) {
                            const int lch = cot * 16 + quad * 4 + reg;   // 0..63
                            const int slot = px * 72 + (lch ^ ((px & 3) << 3));
                            const float a = acc[rw][pt][cot][reg];
                            if (mode == 0) {
                                float c = fmaxf(MU_ * a - THR_, 0.f);
                                short cb16 = f2bf(c);
                                tb_y[slot] = cb16;
                                tb_c[slot] = cb16;
                            } else if (mode == 1) {
                                float yold = bf2f((unsigned short)tb_y[slot]);
                                float cold = bf2f((unsigned short)tb_c[slot]);
                                float c = fmaxf(yold + MU_ * a - THR_, 0.f);
                                tb_y[slot] = f2bf(c + beta * (c - cold));
                                tb_c[slot] = f2bf(c);
                            } else {
                                if (px < 56) {
                                    float yold = bf2f((unsigned short)tb_y[slot]);
                                    float c = fmaxf(yold + MU_ * a - THR_, 0.f);
                                    outp[((size_t)(n * 128 + hh * 64 + lch)) * 3136 + (h0 + rw) * 56 + px] = c;
                                }
                            }
                        }
                    }
                }
            }
        }
        if (mode != 2) {
            __syncthreads();
            for (int item = tid; item < 448; item += 256) {
                int vv = item >> 3, g = item & 7;
                int so = vv * 72 + 8 * (g ^ (vv & 3));
                int s = vv + 2;
                int xo = 8 * ((g + 8 * hh) ^ (s & 7));
#pragma unroll
                for (int rw = 0; rw < 2; ++rw) {
                    short* tb_y = tbase + rw * 9216;
                    short8 yv = *(const short8*)(tb_y + so);
                    short8 cv = *(const short8*)(tb_y + 4608 + so);
                    size_t off = prow[rw] + (size_t)s * 128 + xo;
                    *(short8*)(Yp + off) = yv;
                    *(short8*)(Cp + off) = cv;
                }
            }
        }
        if (hh == 0) __syncthreads();   // tables free before half-1 reuse
    }
}

// ---------------------------------------------------------------------------
// Transpose conv 128->64, row-PAIR blocks: rows r0,r0+1 from a shared 4-row
// Y window, 2 LDS passes over K chunk halves; pass-1 register-prefetched
// (T14). Wave = 64 ci x 16 px; acc[2 rows][4 cit]. Fused r = x - D^T y.
// grid = 448, same sid0 map as conv_fwd.
// LDS: 4x68x72 staging + 2 tables = 57.6 KB, 2 blocks/CU.
// ---------------------------------------------------------------------------
__global__ __launch_bounds__(256, 2) void conv_t(
    const short* __restrict__ Ypb,   // [n][58][68][128] bf16 swz
    const short* __restrict__ Wt2,   // [9][16][64][8] bf16 k-major chunks
    const short* __restrict__ Xp,    // [n][58][68][64] bf16 swz
    short* __restrict__ Rp) {        // [n][58][68][64] bf16 swz
    __shared__ __align__(16) short smem[28800];
    const int bid = blockIdx.x, tid = threadIdx.x;
    const int sid0 = (bid & 7) * 112 + (bid >> 3) * 2;
    const int n = sid0 / 56, r0 = sid0 - n * 56 + 1;
    const int lane = tid & 63, ct = tid >> 6, quad = lane >> 4, l15 = lane & 15;
    const short8* src = (const short8*)(Ypb + ((size_t)(n * 58 + (r0 - 1)) * 68) * 128);
    size_t prowX[2];
    prowX[0] = ((size_t)(n * 58 + r0) * 68) * 64;
    prowX[1] = prowX[0] + 68 * 64;

    // pre-loop coalesced prefetch of x rows (448 short8 items per row)
    short8 xold8[2][2];
    int pvv[2], pg[2]; bool pok[2];
#pragma unroll
    for (int k = 0; k < 2; ++k) {
        int item = tid + k * 256;
        pok[k] = item < 448;
        pvv[k] = item >> 3; pg[k] = item & 7;
        if (pok[k]) {
            int s = pvv[k] + 2;
            int xo = 8 * (pg[k] ^ (s & 7));
#pragma unroll
            for (int rw = 0; rw < 2; ++rw)
                xold8[rw][k] = *(const short8*)(Xp + prowX[rw] + (size_t)s * 64 + xo);
        }
    }

    zero_lds_pads4(smem, tid);
    // stage pass-0 (chunk half 0) of 4 rows, interior slots (1792 items)
    for (int j = tid; j < 1792; j += 256) {
        int sr = j >> 3, w = j & 7;
        int row = sr / 56, s = sr - row * 56 + 2;
        *(short8*)(smem + (row * 68 + s) * 72 + w * 8) = src[(row * 68 + s) * 16 + w];
    }

    f32x4 acc[2][4];                  // [rw][cit] : 64 ci x 16 px per wave
#pragma unroll
    for (int rw = 0; rw < 2; ++rw)
#pragma unroll
        for (int cit = 0; cit < 4; ++cit) acc[rw][cit] = (f32x4){0.f, 0.f, 0.f, 0.f};

    __syncthreads();

    // T14: issue pass-1 staging loads now; latency hides under pass-0 compute
    short8 pf[7];
#pragma unroll
    for (int k = 0; k < 7; ++k) {
        int j = tid + k * 256;
        if (j < 1792) {
            int sr = j >> 3, w = j & 7;
            int row = sr / 56, s = sr - row * 56 + 2;
            pf[k] = src[(row * 68 + s) * 16 + 8 + w];
        }
    }

#pragma unroll
    for (int p = 0; p < 2; ++p) {
        if (p) {
            __syncthreads();          // pass-0 B reads complete
#pragma unroll
            for (int k = 0; k < 7; ++k) {
                int j = tid + k * 256;
                if (j < 1792) {
                    int sr = j >> 3, w = j & 7;
                    int row = sr / 56, s = sr - row * 56 + 2;
                    *(short8*)(smem + (row * 68 + s) * 72 + w * 8) = pf[k];
                }
            }
            __syncthreads();
        }
#pragma unroll
        for (int f = 0; f < 18; ++f) {         // 18 k-frags; A shared by rows
            const int t = f >> 1, sh = f & 1;
            const int dh = t / 3, dw = t % 3;
            const int u = l15 + dw + 1;
            const int phys = (sh * 4 + quad) ^ (u & 7);
            short8 areg[4];
#pragma unroll
            for (int cit = 0; cit < 4; ++cit) {
                const int ci = cit * 16 + l15;
                areg[cit] = *(const short8*)(Wt2 +
                    ((size_t)((t * 16 + (p * 2 + sh) * 4 + quad) * 64 + ci)) * 8);
            }
#pragma unroll
            for (int rw = 0; rw < 2; ++rw) {
                const short8 bv = *(const short8*)(smem +
                    ((dh + rw) * 68 + ct * 16 + u) * 72 + phys * 8);
#pragma unroll
                for (int cit = 0; cit < 4; ++cit)
                    acc[rw][cit] = __builtin_amdgcn_mfma_f32_16x16x32_bf16(areg[cit], bv, acc[rw][cit], 0, 0, 0);
            }
        }
    }

    // ---- epilogue: r = x - acc via LDS bounce (tables beyond staging) ----
    short* tbase = smem + 19584;     // [rw][64 px][72 ch]
#pragma unroll
    for (int rw = 0; rw < 2; ++rw) {
#pragma unroll
        for (int k = 0; k < 2; ++k) if (pok[k]) {
            *(short8*)(tbase + rw * 4608 + pvv[k] * 72 + 8 * (pg[k] ^ (pvv[k] & 3))) = xold8[rw][k];
        }
    }
    __syncthreads();
    {
        const int px = ct * 16 + l15;
#pragma unroll
        for (int rw = 0; rw < 2; ++rw) {
            short* tb = tbase + rw * 4608;
#pragma unroll
            for (int cit = 0; cit < 4; ++cit) {
#pragma unroll
                for (int reg = 0; reg < 4; ++reg) {
                    const int cir = cit * 16 + quad * 4 + reg;
                    const int slot = px * 72 + (cir ^ ((px & 3) << 3));
                    float xo = bf2f((unsigned short)tb[slot]);
                    tb[slot] = f2bf(xo - acc[rw][cit][reg]);
                }
            }
        }
    }
    __syncthreads();
    for (int item = tid; item < 448; item += 256) {
        int vv = item >> 3, g = item & 7;
        int so = vv * 72 + 8 * (g ^ (vv & 3));
        int s = vv + 2;
        int xo = 8 * (g ^ (s & 7));
#pragma unroll
        for (int rw = 0; rw < 2; ++rw) {
            short8 val = *(const short8*)(tbase + rw * 4608 + so);
            *(short8*)(Rp + prowX[rw] + (size_t)s * 64 + xo) = val;
        }
    }
}

// ---------------------------------------------------------------------------
extern "C" void kernel_launch(void* const* d_in, const int* in_sizes, int n_in,
                              void* d_out, int out_size, void* d_ws, size_t ws_size,
                              hipStream_t stream) {
    const float* x = (const float*)d_in[0];   // [16,64,56,56] fp32
    const float* W = (const float*)d_in[1];   // [128,64,3,3]  fp32
    float* out = (float*)d_out;               // [16,128,56,56] fp32

    // ws layout (all bf16): Xp | Rp | Yp | Cp | Wf2 | Wt2  (~49 MB)
    const size_t XPN = (size_t)16 * 58 * 68 * 64;   // 4,038,656
    const size_t YPN = 2 * XPN;                      // 8,077,312
    short* Xp = (short*)d_ws;
    short* Rp = Xp + XPN;
    short* Yp = Rp + XPN;
    short* Cp = Yp + YPN;
    short* Wf2 = Cp + YPN;                // 73728 shorts
    short* Wt2 = Wf2 + 73728;             // 73728 shorts

    const int prep_blocks = ZB_ + 32 + 58 * 16;     // 1164
    hipLaunchKernelGGL(prep_kernel, dim3(prep_blocks), dim3(256), 0, stream,
                       x, W, Rp, Yp, Xp, Wf2, Wt2);

    dim3 b(256, 1, 1);
    // it0: c = shrink(MU * conv(x)); y = cp = c
    hipLaunchKernelGGL(conv_fwd, dim3(448), b, 0, stream, Xp, Wf2, Yp, Cp,
                       (float*)nullptr, 0, 0.f);
    double t = 1.0;
    for (int it = 1; it <= 5; ++it) {
        hipLaunchKernelGGL(conv_t, dim3(448), b, 0, stream, Yp, Wt2, Xp, Rp);
        double tn = (1.0 + sqrt(1.0 + 4.0 * t * t)) / 2.0;
        float beta = (float)((t - 1.0) / tn);
        hipLaunchKernelGGL(conv_fwd, dim3(448), b, 0, stream, Rp, Wf2, Yp, Cp,
                           (it == 5) ? out : (float*)nullptr, (it == 5) ? 2 : 1,
                           beta);
        t = tn;
    }
}